// Round 19
// baseline (83.980 us; speedup 1.0000x reference)
//
#include <hip/hip_runtime.h>
#include <math.h>

#define BB 4
#define NN 8192
#define LL 512
#define NSUB 1024

#define AUX_BLOCKS 64
#define SL_BLOCKS 48
#define CH_BLOCKS 512         // 8 (b,dir) x 64 row-groups of 128 rows
#define PREP_BLOCKS 256

// ws float slot map (no atomics, no init pass):
#define PPS_OFF 0             // 256 prep partials: sum |p|^2 (both sets)
#define CHS_OFF 256           // 512 chamfer partials: sum of per-row max_h
#define DNS_OFF 768           // 16 density sums, then 16 sumsq at +16
#define KL_OFF  800           // 48 kl partials
#define SIZ_OFF 848           // 48 sizing partials
#define MAT_OFF 896           // 48 material partials
#define FRAG_OFF ((size_t)8192)
#define FRAG_SET ((size_t)BB * NN * 32)   // 1 MiB per role/set

typedef __bf16 bf16x8 __attribute__((ext_vector_type(8)));
typedef float f32x16 __attribute__((ext_vector_type(16)));

// f32 -> bf16 (RNE) and back, raw ushort
__device__ inline unsigned short f2bf(float f) {
    unsigned u = __float_as_uint(f);
    unsigned r = (u + 0x7FFFu + ((u >> 16) & 1u)) >> 16;
    return (unsigned short)r;
}
__device__ inline float bf2f(unsigned short h) {
    return __uint_as_float(((unsigned)h) << 16);
}
__device__ inline unsigned pk(unsigned short lo, unsigned short hi) {
    return (unsigned)lo | ((unsigned)hi << 16);
}

__device__ inline float blockReduceSum256(float v) {
    __shared__ float red[4];
    #pragma unroll
    for (int o = 32; o; o >>= 1) v += __shfl_down(v, o);
    __syncthreads();
    if ((threadIdx.x & 63) == 0) red[threadIdx.x >> 6] = v;
    __syncthreads();
    return red[0] + red[1] + red[2] + red[3];
}

// Build MFMA fragments + per-block |p|^2 partial. K map (A entry / B entry):
//  0-2: ph,qh  3-5: pl,qh  6-8: ph,ql  9-11: pl,ql  -> (ph+pl)·(qh+ql)
//  12: 1,wh  13: 1,wl  14: 1,wl2  15: 0,0           -> w = -0.5|q|^2
__global__ __launch_bounds__(256) void prep_frags_kernel(
    const float* __restrict__ pred, const float* __restrict__ targ,
    unsigned char* __restrict__ frag, float* __restrict__ ws) {
    const int i = blockIdx.x * 256 + threadIdx.x;   // 0 .. 2*BB*NN-1
    const int s = i >> 15;
    const int r = i & (BB * NN - 1);
    const int b = r >> 13;
    const int p = r & (NN - 1);
    const float* pos = (s ? targ : pred) + (size_t)r * 3;
    const float x = pos[0], y = pos[1], z = pos[2];
    const unsigned short hx = f2bf(x), hy = f2bf(y), hz = f2bf(z);
    const unsigned short lx = f2bf(x - bf2f(hx));
    const unsigned short ly = f2bf(y - bf2f(hy));
    const unsigned short lz = f2bf(z - bf2f(hz));
    const float pp = fmaf(x, x, fmaf(y, y, z * z));
    const float w = -0.5f * pp;
    const unsigned short wh = f2bf(w);
    const float wr = w - bf2f(wh);
    const unsigned short wl = f2bf(wr);
    const unsigned short wl2 = f2bf(wr - bf2f(wl));
    const unsigned short ONE = 0x3F80;

    uint4 a0, a1, b0, b1;
    a0.x = pk(hx, hy); a0.y = pk(hz, lx); a0.z = pk(ly, lz); a0.w = pk(hx, hy);
    a1.x = pk(hz, lx); a1.y = pk(ly, lz); a1.z = pk(ONE, ONE); a1.w = pk(ONE, 0);
    b0.x = pk(hx, hy); b0.y = pk(hz, hx); b0.z = pk(hy, hz); b0.w = pk(lx, ly);
    b1.x = pk(lz, lx); b1.y = pk(ly, lz); b1.z = pk(wh, wl); b1.w = pk(wl2, 0);

    uint4* Adst = (uint4*)(frag + (size_t)s * FRAG_SET) + (size_t)r * 2;
    Adst[0] = a0;
    Adst[1] = a1;
    uint4* Bdst = (uint4*)(frag + (2 + s) * FRAG_SET);
    const size_t bi = (size_t)b * NN * 2 + (size_t)(p >> 5) * 64 + (p & 31);
    Bdst[bi] = b0;
    Bdst[bi + 32] = b1;

    float sum = blockReduceSum256(pp);
    if (threadIdx.x == 0) ws[PPS_OFF + blockIdx.x] = sum;
}

// grid 576 x 256:
//  bid < 16            -> density (chunk = bid&3, b = bid>>2)  [overlaps]
//  16 <= bid < 64      -> kl + sizing + material
//  bid >= 64           -> chamfer: cid = bid-64: rg = cid&63, bd = cid>>6
// Chamfer block: 128 query rows (4 A-tile STREAMS) x all 8192 targets.
// 4 independent MFMA->merge streams fill each other's result-hazard
// windows (R8-R17 wall: ~35% idle with only 2 streams). Spill-proof
// budget vs R18: launch_bounds(256,4), NO ring (plain 2-deep prefetch,
// 2 pairs in flight), ONE d live at a time. ~118 VGPR. Plain zero C
// (R14). Cross-wave rowmax MAX-merge before summing (R13). No inline
// asm on MFMA outputs (R10).
__global__ __launch_bounds__(256, 4) void mega_kernel(
    const float* __restrict__ pred,
    const unsigned char* __restrict__ frag,
    const float* __restrict__ mu, const float* __restrict__ logvar,
    const float* __restrict__ psiz, const float* __restrict__ tsiz,
    const float* __restrict__ pmat, const float* __restrict__ tmat,
    const int* __restrict__ sub_idx, float* __restrict__ ws) {
    __shared__ __align__(16) unsigned char smem[16384];
    const int tid = threadIdx.x;
    const int bid = blockIdx.x;

    if (bid >= AUX_BLOCKS) {        // ---- chamfer via MFMA ----
        const int cid = bid - AUX_BLOCKS;
        const int rg = cid & 63;
        const int bd = cid >> 6;
        const int b = bd >> 1;
        const int dir = bd & 1;
        const int As = dir;          // query set
        const int Bs = dir ^ 1;      // target set
        const int w = tid >> 6, lane = tid & 63;
        const int lo5 = lane & 31, sel = lane >> 5;

        const uint4* Ap = (const uint4*)(frag + (size_t)As * FRAG_SET) +
                          (size_t)b * NN * 2;
        const int qbase = rg * 128;
        const bf16x8 A0 = __builtin_bit_cast(
            bf16x8, Ap[(size_t)(qbase + lo5) * 2 + sel]);
        const bf16x8 A1 = __builtin_bit_cast(
            bf16x8, Ap[(size_t)(qbase + 32 + lo5) * 2 + sel]);
        const bf16x8 A2 = __builtin_bit_cast(
            bf16x8, Ap[(size_t)(qbase + 64 + lo5) * 2 + sel]);
        const bf16x8 A3 = __builtin_bit_cast(
            bf16x8, Ap[(size_t)(qbase + 96 + lo5) * 2 + sel]);

        // wave w's quarter: 2048 targets = 64 tiles; consume 1 tile/iter
        const uint4* Bq = (const uint4*)(frag + (size_t)(2 + Bs) * FRAG_SET) +
                          (size_t)b * NN * 2 + (size_t)w * 4096 + lane;

        f32x16 st0, st1, st2, st3;
        #pragma unroll
        for (int i = 0; i < 16; ++i) {
            st0[i] = -3e38f; st1[i] = -3e38f;
            st2[i] = -3e38f; st3[i] = -3e38f;
        }
        const f32x16 zc = {};

        // 2-deep single-tile prefetch: cur + next in flight (16 regs)
        uint4 cur = Bq[0];
        uint4 nxt = Bq[64];
        #pragma unroll 1
        for (int it = 0; it < 64; ++it) {
            const int pf = (it < 62) ? (it + 2) : it;
            uint4 m0 = Bq[(size_t)pf * 64];
            const bf16x8 B0 = __builtin_bit_cast(bf16x8, cur);
            {
                f32x16 d = __builtin_amdgcn_mfma_f32_32x32x16_bf16(
                    A0, B0, zc, 0, 0, 0);
                #pragma unroll
                for (int i = 0; i < 16; ++i) st0[i] = fmaxf(st0[i], d[i]);
            }
            {
                f32x16 d = __builtin_amdgcn_mfma_f32_32x32x16_bf16(
                    A1, B0, zc, 0, 0, 0);
                #pragma unroll
                for (int i = 0; i < 16; ++i) st1[i] = fmaxf(st1[i], d[i]);
            }
            {
                f32x16 d = __builtin_amdgcn_mfma_f32_32x32x16_bf16(
                    A2, B0, zc, 0, 0, 0);
                #pragma unroll
                for (int i = 0; i < 16; ++i) st2[i] = fmaxf(st2[i], d[i]);
            }
            {
                f32x16 d = __builtin_amdgcn_mfma_f32_32x32x16_bf16(
                    A3, B0, zc, 0, 0, 0);
                #pragma unroll
                for (int i = 0; i < 16; ++i) st3[i] = fmaxf(st3[i], d[i]);
            }
            cur = nxt;
            nxt = m0;
        }

        // max over the 32 target columns (lane&31) per accumulator
        #pragma unroll
        for (int m = 1; m <= 16; m <<= 1) {
            #pragma unroll
            for (int i = 0; i < 16; ++i) {
                st0[i] = fmaxf(st0[i], __shfl_xor(st0[i], m));
                st1[i] = fmaxf(st1[i], __shfl_xor(st1[i], m));
                st2[i] = fmaxf(st2[i], __shfl_xor(st2[i], m));
                st3[i] = fmaxf(st3[i], __shfl_xor(st3[i], m));
            }
        }
        // cross-wave rowmax merge (each wave holds a target-QUARTER max):
        // rowmax[w][128 rows] -> max over w -> sum rows.
        float* sm = (float*)smem;
        if (lo5 == 0) {
            #pragma unroll
            for (int i = 0; i < 16; ++i) {
                const int r = (i & 3) + 8 * (i >> 2) + 4 * sel;
                sm[w * 128 + r] = st0[i];
                sm[w * 128 + 32 + r] = st1[i];
                sm[w * 128 + 64 + r] = st2[i];
                sm[w * 128 + 96 + r] = st3[i];
            }
        }
        __syncthreads();
        float v = 0.0f;
        if (tid < 128) {
            v = fmaxf(fmaxf(sm[tid], sm[128 + tid]),
                      fmaxf(sm[256 + tid], sm[384 + tid]));
        }
        __syncthreads();
        float s = blockReduceSum256(v);
        if (tid == 0) ws[CHS_OFF + cid] = s;   // sum of row max_h
        return;
    }

    if (bid < 16) {                 // ---- density ----
        float4* pts = (float4*)smem;
        const int chunk = bid & 3;
        const int b = bid >> 2;
        for (int k = tid; k < NSUB; k += 256) {
            int idx = sub_idx[k];
            const float* p = pred + ((size_t)b * NN + idx) * 3;
            float x = p[0], y = p[1], z = p[2];
            pts[k] = make_float4(x, y, z, -0.5f * fmaf(x, x, fmaf(y, y, z * z)));
        }
        __syncthreads();
        const int i = chunk * 256 + tid;
        const float4 me = pts[i];
        float h0 = -1e30f, h1 = -1e30f, h2 = -1e30f, h3 = -1e30f;
        #pragma unroll 4
        for (int j = 0; j < NSUB; j += 4) {
            float4 q0 = pts[j + 0], q1 = pts[j + 1], q2 = pts[j + 2], q3 = pts[j + 3];
            float t0 = fmaf(me.z, q0.z, q0.w);
            t0 = fmaf(me.y, q0.y, t0); t0 = fmaf(me.x, q0.x, t0);
            t0 = (j + 0 == i) ? -1e30f : t0; h0 = fmaxf(h0, t0);
            float t1 = fmaf(me.z, q1.z, q1.w);
            t1 = fmaf(me.y, q1.y, t1); t1 = fmaf(me.x, q1.x, t1);
            t1 = (j + 1 == i) ? -1e30f : t1; h1 = fmaxf(h1, t1);
            float t2 = fmaf(me.z, q2.z, q2.w);
            t2 = fmaf(me.y, q2.y, t2); t2 = fmaf(me.x, q2.x, t2);
            t2 = (j + 2 == i) ? -1e30f : t2; h2 = fmaxf(h2, t2);
            float t3 = fmaf(me.z, q3.z, q3.w);
            t3 = fmaf(me.y, q3.y, t3); t3 = fmaf(me.x, q3.x, t3);
            t3 = (j + 3 == i) ? -1e30f : t3; h3 = fmaxf(h3, t3);
        }
        float h = fmaxf(fmaxf(h0, h1), fmaxf(h2, h3));
        float pp = fmaf(me.x, me.x, fmaf(me.y, me.y, me.z * me.z));
        float m = pp - 2.0f * h;        // nn squared distance
        float s = blockReduceSum256(m); __syncthreads();
        float ss = blockReduceSum256(m * m);
        if (tid == 0) {
            ws[DNS_OFF + bid] = s;
            ws[DNS_OFF + 16 + bid] = ss;
        }
    } else {                        // ---- kl + sizing + material ----
        const int r = bid - 16;
        const int stride = SL_BLOCKS * 256;
        const int g0 = r * 256 + tid;
        float skl = 0.0f;
        for (int i = g0; i < BB * LL; i += stride) {
            float m = mu[i], lv = logvar[i];
            skl += 1.0f + lv - m * m - expf(lv);
        }
        float ssz = 0.0f;
        for (int i = g0; i < BB * NN; i += stride) {
            float d = psiz[i] - tsiz[i];
            ssz = fmaf(d, d, ssz);
        }
        float smt = 0.0f;
        for (int i = g0; i < BB * NN * 4; i += stride) {
            float d = pmat[i] - tmat[i];
            smt = fmaf(d, d, smt);
        }
        skl = blockReduceSum256(skl); __syncthreads();
        ssz = blockReduceSum256(ssz); __syncthreads();
        smt = blockReduceSum256(smt);
        if (tid == 0) {
            ws[KL_OFF + r] = skl;
            ws[SIZ_OFF + r] = ssz;
            ws[MAT_OFF + r] = smt;
        }
    }
}

__global__ __launch_bounds__(256) void finalize_kernel(
    const float* __restrict__ ws, float* __restrict__ out) {
    const int t = threadIdx.x;
    float pp = ws[PPS_OFF + t];
    float ch = ws[CHS_OFF + t] + ws[CHS_OFF + 256 + t];
    float kl = (t < SL_BLOCKS) ? ws[KL_OFF + t] : 0.0f;
    float sz = (t < SL_BLOCKS) ? ws[SIZ_OFF + t] : 0.0f;
    float mt = (t < SL_BLOCKS) ? ws[MAT_OFF + t] : 0.0f;
    float s_pp = blockReduceSum256(pp); __syncthreads();
    float s_ch = blockReduceSum256(ch); __syncthreads();
    float s_kl = blockReduceSum256(kl); __syncthreads();
    float s_sz = blockReduceSum256(sz); __syncthreads();
    float s_mt = blockReduceSum256(mt);
    if (t == 0) {
        float den = 0.0f;
        #pragma unroll
        for (int b = 0; b < BB; ++b) {
            float s = ws[DNS_OFF + 4 * b + 0] + ws[DNS_OFF + 4 * b + 1] +
                      ws[DNS_OFF + 4 * b + 2] + ws[DNS_OFF + 4 * b + 3];
            float q = ws[DNS_OFF + 16 + 4 * b + 0] + ws[DNS_OFF + 16 + 4 * b + 1] +
                      ws[DNS_OFF + 16 + 4 * b + 2] + ws[DNS_OFF + 16 + 4 * b + 3];
            float var = (q - s * s / (float)NSUB) / (float)(NSUB - 1);
            den += sqrtf(fmaxf(var, 0.0f));
        }
        den *= (1.0f / BB);
        float cd = (s_pp - 2.0f * s_ch) / (float)(BB * NN);
        float klv = -0.5f * s_kl / (float)(BB * LL);
        float sizing = s_sz / (float)(BB * NN);
        float material = s_mt / (float)(BB * NN * 4);
        out[0] = cd + 0.001f * klv + 0.1f * den + 0.05f * sizing +
                 0.1f * material;
    }
}

extern "C" void kernel_launch(void* const* d_in, const int* in_sizes, int n_in,
                              void* d_out, int out_size, void* d_ws,
                              size_t ws_size, hipStream_t stream) {
    const float* pred_pos = (const float*)d_in[0];
    const float* pred_siz = (const float*)d_in[1];
    const float* pred_mat = (const float*)d_in[2];
    const float* targ_pos = (const float*)d_in[3];
    const float* targ_siz = (const float*)d_in[4];
    const float* targ_mat = (const float*)d_in[5];
    const float* mu = (const float*)d_in[6];
    const float* logvar = (const float*)d_in[7];
    const int* sub_idx = (const int*)d_in[8];
    float* out = (float*)d_out;
    float* ws = (float*)d_ws;
    unsigned char* frag = (unsigned char*)d_ws + FRAG_OFF;

    prep_frags_kernel<<<PREP_BLOCKS, 256, 0, stream>>>(pred_pos, targ_pos,
                                                       frag, ws);
    mega_kernel<<<AUX_BLOCKS + CH_BLOCKS, 256, 0, stream>>>(
        pred_pos, frag, mu, logvar, pred_siz, targ_siz, pred_mat, targ_mat,
        sub_idx, ws);
    finalize_kernel<<<1, 256, 0, stream>>>(ws, out);
}

// Round 20
// 40.062 us; speedup vs baseline: 2.0962x; 2.0962x over previous
//
#include <hip/hip_runtime.h>
#include <math.h>

#define BB 4
#define NN 8192
#define LL 512
#define NSUB 1024

#define AUX_BLOCKS 64
#define SL_BLOCKS 48
#define CH_BLOCKS 1024        // 8 (b,dir) x 128 row-groups of 64 rows
#define PREP_BLOCKS 256

// ws float slot map (no atomics, no init pass):
#define PPS_OFF 0             // 256 prep partials: sum |p|^2 (both sets)
#define CHS_OFF 256           // 1024 chamfer partials: sum of per-row max_h
#define DNS_OFF 1280          // 16 density sums, then 16 sumsq at +16
#define KL_OFF  1312          // 48 kl partials
#define SIZ_OFF 1360          // 48 sizing partials
#define MAT_OFF 1408          // 48 material partials
#define FRAG_OFF ((size_t)8192)
#define FRAG_SET ((size_t)BB * NN * 32)   // 1 MiB per role/set

typedef __bf16 bf16x8 __attribute__((ext_vector_type(8)));
typedef float f32x16 __attribute__((ext_vector_type(16)));

// f32 -> bf16 (RNE) and back, raw ushort
__device__ inline unsigned short f2bf(float f) {
    unsigned u = __float_as_uint(f);
    unsigned r = (u + 0x7FFFu + ((u >> 16) & 1u)) >> 16;
    return (unsigned short)r;
}
__device__ inline float bf2f(unsigned short h) {
    return __uint_as_float(((unsigned)h) << 16);
}
__device__ inline unsigned pk(unsigned short lo, unsigned short hi) {
    return (unsigned)lo | ((unsigned)hi << 16);
}

__device__ inline float blockReduceSum256(float v) {
    __shared__ float red[4];
    #pragma unroll
    for (int o = 32; o; o >>= 1) v += __shfl_down(v, o);
    __syncthreads();
    if ((threadIdx.x & 63) == 0) red[threadIdx.x >> 6] = v;
    __syncthreads();
    return red[0] + red[1] + red[2] + red[3];
}

// Build MFMA fragments + per-block |p|^2 partial. K map (A entry / B entry):
//  0-2: ph,qh  3-5: pl,qh  6-8: ph,ql  9-11: pl,ql  -> (ph+pl)·(qh+ql)
//  12: 1,wh  13: 1,wl  14: 1,wl2  15: 0,0           -> w = -0.5|q|^2
__global__ __launch_bounds__(256) void prep_frags_kernel(
    const float* __restrict__ pred, const float* __restrict__ targ,
    unsigned char* __restrict__ frag, float* __restrict__ ws) {
    const int i = blockIdx.x * 256 + threadIdx.x;   // 0 .. 2*BB*NN-1
    const int s = i >> 15;
    const int r = i & (BB * NN - 1);
    const int b = r >> 13;
    const int p = r & (NN - 1);
    const float* pos = (s ? targ : pred) + (size_t)r * 3;
    const float x = pos[0], y = pos[1], z = pos[2];
    const unsigned short hx = f2bf(x), hy = f2bf(y), hz = f2bf(z);
    const unsigned short lx = f2bf(x - bf2f(hx));
    const unsigned short ly = f2bf(y - bf2f(hy));
    const unsigned short lz = f2bf(z - bf2f(hz));
    const float pp = fmaf(x, x, fmaf(y, y, z * z));
    const float w = -0.5f * pp;
    const unsigned short wh = f2bf(w);
    const float wr = w - bf2f(wh);
    const unsigned short wl = f2bf(wr);
    const unsigned short wl2 = f2bf(wr - bf2f(wl));
    const unsigned short ONE = 0x3F80;

    uint4 a0, a1, b0, b1;
    a0.x = pk(hx, hy); a0.y = pk(hz, lx); a0.z = pk(ly, lz); a0.w = pk(hx, hy);
    a1.x = pk(hz, lx); a1.y = pk(ly, lz); a1.z = pk(ONE, ONE); a1.w = pk(ONE, 0);
    b0.x = pk(hx, hy); b0.y = pk(hz, hx); b0.z = pk(hy, hz); b0.w = pk(lx, ly);
    b1.x = pk(lz, lx); b1.y = pk(ly, lz); b1.z = pk(wh, wl); b1.w = pk(wl2, 0);

    uint4* Adst = (uint4*)(frag + (size_t)s * FRAG_SET) + (size_t)r * 2;
    Adst[0] = a0;
    Adst[1] = a1;
    uint4* Bdst = (uint4*)(frag + (2 + s) * FRAG_SET);
    const size_t bi = (size_t)b * NN * 2 + (size_t)(p >> 5) * 64 + (p & 31);
    Bdst[bi] = b0;
    Bdst[bi + 32] = b1;

    float sum = blockReduceSum256(pp);
    if (threadIdx.x == 0) ws[PPS_OFF + blockIdx.x] = sum;
}

// grid 1088 x 256:
//  bid < 16            -> density (chunk = bid&3, b = bid>>2)  [overlaps]
//  16 <= bid < 64      -> kl + sizing + material
//  bid >= 64           -> chamfer: cid = bid-64: rg = cid&127, bd = cid>>7
// Chamfer block: 64 query rows x all 8192 targets; wave w owns target
// quarter [w*2048,(w+1)*2048). B direct from cache with a 4-SLOT register
// ring prefetch (8 loads in flight/wave). 2 A-tile streams — R18 (4
// streams, (256,3)) spilled to scratch, R19 (4 streams, (256,4)) drowned
// in AGPR<->VGPR shuttling; 2 streams is the register-file sweet spot.
// Plain zero C (R14: opaque-zc costs occupancy). Cross-wave rowmax
// MAX-merge before summing (R13). No inline asm on MFMA outputs (R10).
__global__ __launch_bounds__(256, 4) void mega_kernel(
    const float* __restrict__ pred,
    const unsigned char* __restrict__ frag,
    const float* __restrict__ mu, const float* __restrict__ logvar,
    const float* __restrict__ psiz, const float* __restrict__ tsiz,
    const float* __restrict__ pmat, const float* __restrict__ tmat,
    const int* __restrict__ sub_idx, float* __restrict__ ws) {
    __shared__ __align__(16) unsigned char smem[16384];
    const int tid = threadIdx.x;
    const int bid = blockIdx.x;

    if (bid >= AUX_BLOCKS) {        // ---- chamfer via MFMA ----
        const int cid = bid - AUX_BLOCKS;
        const int rg = cid & 127;
        const int bd = cid >> 7;
        const int b = bd >> 1;
        const int dir = bd & 1;
        const int As = dir;          // query set
        const int Bs = dir ^ 1;      // target set
        const int w = tid >> 6, lane = tid & 63;
        const int lo5 = lane & 31, sel = lane >> 5;

        const uint4* Ap = (const uint4*)(frag + (size_t)As * FRAG_SET) +
                          (size_t)b * NN * 2;
        const int qbase = rg * 64;
        const bf16x8 A0 = __builtin_bit_cast(
            bf16x8, Ap[(size_t)(qbase + lo5) * 2 + sel]);
        const bf16x8 A1 = __builtin_bit_cast(
            bf16x8, Ap[(size_t)(qbase + 32 + lo5) * 2 + sel]);

        // wave w's 64 target tiles (tile = 32 targets = 64 uint4);
        // iteration it consumes tile-pair at uint4 offsets it*128, it*128+64
        const uint4* Bq = (const uint4*)(frag + (size_t)(2 + Bs) * FRAG_SET) +
                          (size_t)b * NN * 2 + (size_t)w * 4096 + lane;

        f32x16 st0, st1;
        #pragma unroll
        for (int i = 0; i < 16; ++i) { st0[i] = -3e38f; st1[i] = -3e38f; }
        const f32x16 zc = {};

        // 4-slot prefetch ring: slots hold pairs for its base..base+3
        uint4 s0a = Bq[0],   s0b = Bq[64];
        uint4 s1a = Bq[128], s1b = Bq[192];
        uint4 s2a = Bq[256], s2b = Bq[320];
        uint4 s3a = Bq[384], s3b = Bq[448];

        #pragma unroll 1
        for (int c = 0; c < 8; ++c) {
            const int base = c * 4;
            const int nx = (c < 7) ? (base + 4) : base;  // clamp: reload self
            {   // k=0: use slot0, refill for it = nx+0
                const bf16x8 B0 = __builtin_bit_cast(bf16x8, s0a);
                const bf16x8 B1 = __builtin_bit_cast(bf16x8, s0b);
                f32x16 d0 = __builtin_amdgcn_mfma_f32_32x32x16_bf16(
                    A0, B0, zc, 0, 0, 0);
                f32x16 d1 = __builtin_amdgcn_mfma_f32_32x32x16_bf16(
                    A0, B1, zc, 0, 0, 0);
                f32x16 e0 = __builtin_amdgcn_mfma_f32_32x32x16_bf16(
                    A1, B0, zc, 0, 0, 0);
                f32x16 e1 = __builtin_amdgcn_mfma_f32_32x32x16_bf16(
                    A1, B1, zc, 0, 0, 0);
                s0a = Bq[(size_t)(nx + 0) * 128];
                s0b = Bq[(size_t)(nx + 0) * 128 + 64];
                #pragma unroll
                for (int i = 0; i < 16; ++i) {
                    st0[i] = fmaxf(fmaxf(st0[i], d0[i]), d1[i]);
                    st1[i] = fmaxf(fmaxf(st1[i], e0[i]), e1[i]);
                }
            }
            {   // k=1
                const bf16x8 B0 = __builtin_bit_cast(bf16x8, s1a);
                const bf16x8 B1 = __builtin_bit_cast(bf16x8, s1b);
                f32x16 d0 = __builtin_amdgcn_mfma_f32_32x32x16_bf16(
                    A0, B0, zc, 0, 0, 0);
                f32x16 d1 = __builtin_amdgcn_mfma_f32_32x32x16_bf16(
                    A0, B1, zc, 0, 0, 0);
                f32x16 e0 = __builtin_amdgcn_mfma_f32_32x32x16_bf16(
                    A1, B0, zc, 0, 0, 0);
                f32x16 e1 = __builtin_amdgcn_mfma_f32_32x32x16_bf16(
                    A1, B1, zc, 0, 0, 0);
                s1a = Bq[(size_t)(nx + 1) * 128];
                s1b = Bq[(size_t)(nx + 1) * 128 + 64];
                #pragma unroll
                for (int i = 0; i < 16; ++i) {
                    st0[i] = fmaxf(fmaxf(st0[i], d0[i]), d1[i]);
                    st1[i] = fmaxf(fmaxf(st1[i], e0[i]), e1[i]);
                }
            }
            {   // k=2
                const bf16x8 B0 = __builtin_bit_cast(bf16x8, s2a);
                const bf16x8 B1 = __builtin_bit_cast(bf16x8, s2b);
                f32x16 d0 = __builtin_amdgcn_mfma_f32_32x32x16_bf16(
                    A0, B0, zc, 0, 0, 0);
                f32x16 d1 = __builtin_amdgcn_mfma_f32_32x32x16_bf16(
                    A0, B1, zc, 0, 0, 0);
                f32x16 e0 = __builtin_amdgcn_mfma_f32_32x32x16_bf16(
                    A1, B0, zc, 0, 0, 0);
                f32x16 e1 = __builtin_amdgcn_mfma_f32_32x32x16_bf16(
                    A1, B1, zc, 0, 0, 0);
                s2a = Bq[(size_t)(nx + 2) * 128];
                s2b = Bq[(size_t)(nx + 2) * 128 + 64];
                #pragma unroll
                for (int i = 0; i < 16; ++i) {
                    st0[i] = fmaxf(fmaxf(st0[i], d0[i]), d1[i]);
                    st1[i] = fmaxf(fmaxf(st1[i], e0[i]), e1[i]);
                }
            }
            {   // k=3
                const bf16x8 B0 = __builtin_bit_cast(bf16x8, s3a);
                const bf16x8 B1 = __builtin_bit_cast(bf16x8, s3b);
                f32x16 d0 = __builtin_amdgcn_mfma_f32_32x32x16_bf16(
                    A0, B0, zc, 0, 0, 0);
                f32x16 d1 = __builtin_amdgcn_mfma_f32_32x32x16_bf16(
                    A0, B1, zc, 0, 0, 0);
                f32x16 e0 = __builtin_amdgcn_mfma_f32_32x32x16_bf16(
                    A1, B0, zc, 0, 0, 0);
                f32x16 e1 = __builtin_amdgcn_mfma_f32_32x32x16_bf16(
                    A1, B1, zc, 0, 0, 0);
                s3a = Bq[(size_t)(nx + 3) * 128];
                s3b = Bq[(size_t)(nx + 3) * 128 + 64];
                #pragma unroll
                for (int i = 0; i < 16; ++i) {
                    st0[i] = fmaxf(fmaxf(st0[i], d0[i]), d1[i]);
                    st1[i] = fmaxf(fmaxf(st1[i], e0[i]), e1[i]);
                }
            }
        }

        // max over the 32 target columns (lane&31) per accumulator
        #pragma unroll
        for (int m = 1; m <= 16; m <<= 1) {
            #pragma unroll
            for (int i = 0; i < 16; ++i) {
                st0[i] = fmaxf(st0[i], __shfl_xor(st0[i], m));
                st1[i] = fmaxf(st1[i], __shfl_xor(st1[i], m));
            }
        }
        // cross-wave rowmax merge (each wave holds a target-QUARTER max):
        // rowmax[w][64 rows] -> max over w -> sum rows.
        float* sm = (float*)smem;
        if (lo5 == 0) {
            #pragma unroll
            for (int i = 0; i < 16; ++i) {
                const int r = (i & 3) + 8 * (i >> 2) + 4 * sel;
                sm[w * 64 + r] = st0[i];
                sm[w * 64 + 32 + r] = st1[i];
            }
        }
        __syncthreads();
        if (tid < 64) {
            float v = fmaxf(fmaxf(sm[tid], sm[64 + tid]),
                            fmaxf(sm[128 + tid], sm[192 + tid]));
            #pragma unroll
            for (int o = 32; o; o >>= 1) v += __shfl_down(v, o);
            if (tid == 0) ws[CHS_OFF + cid] = v;   // sum of row max_h
        }
        return;
    }

    if (bid < 16) {                 // ---- density ----
        float4* pts = (float4*)smem;
        const int chunk = bid & 3;
        const int b = bid >> 2;
        for (int k = tid; k < NSUB; k += 256) {
            int idx = sub_idx[k];
            const float* p = pred + ((size_t)b * NN + idx) * 3;
            float x = p[0], y = p[1], z = p[2];
            pts[k] = make_float4(x, y, z, -0.5f * fmaf(x, x, fmaf(y, y, z * z)));
        }
        __syncthreads();
        const int i = chunk * 256 + tid;
        const float4 me = pts[i];
        float h0 = -1e30f, h1 = -1e30f, h2 = -1e30f, h3 = -1e30f;
        #pragma unroll 4
        for (int j = 0; j < NSUB; j += 4) {
            float4 q0 = pts[j + 0], q1 = pts[j + 1], q2 = pts[j + 2], q3 = pts[j + 3];
            float t0 = fmaf(me.z, q0.z, q0.w);
            t0 = fmaf(me.y, q0.y, t0); t0 = fmaf(me.x, q0.x, t0);
            t0 = (j + 0 == i) ? -1e30f : t0; h0 = fmaxf(h0, t0);
            float t1 = fmaf(me.z, q1.z, q1.w);
            t1 = fmaf(me.y, q1.y, t1); t1 = fmaf(me.x, q1.x, t1);
            t1 = (j + 1 == i) ? -1e30f : t1; h1 = fmaxf(h1, t1);
            float t2 = fmaf(me.z, q2.z, q2.w);
            t2 = fmaf(me.y, q2.y, t2); t2 = fmaf(me.x, q2.x, t2);
            t2 = (j + 2 == i) ? -1e30f : t2; h2 = fmaxf(h2, t2);
            float t3 = fmaf(me.z, q3.z, q3.w);
            t3 = fmaf(me.y, q3.y, t3); t3 = fmaf(me.x, q3.x, t3);
            t3 = (j + 3 == i) ? -1e30f : t3; h3 = fmaxf(h3, t3);
        }
        float h = fmaxf(fmaxf(h0, h1), fmaxf(h2, h3));
        float pp = fmaf(me.x, me.x, fmaf(me.y, me.y, me.z * me.z));
        float m = pp - 2.0f * h;        // nn squared distance
        float s = blockReduceSum256(m); __syncthreads();
        float ss = blockReduceSum256(m * m);
        if (tid == 0) {
            ws[DNS_OFF + bid] = s;
            ws[DNS_OFF + 16 + bid] = ss;
        }
    } else {                        // ---- kl + sizing + material ----
        const int r = bid - 16;
        const int stride = SL_BLOCKS * 256;
        const int g0 = r * 256 + tid;
        float skl = 0.0f;
        for (int i = g0; i < BB * LL; i += stride) {
            float m = mu[i], lv = logvar[i];
            skl += 1.0f + lv - m * m - expf(lv);
        }
        float ssz = 0.0f;
        for (int i = g0; i < BB * NN; i += stride) {
            float d = psiz[i] - tsiz[i];
            ssz = fmaf(d, d, ssz);
        }
        float smt = 0.0f;
        for (int i = g0; i < BB * NN * 4; i += stride) {
            float d = pmat[i] - tmat[i];
            smt = fmaf(d, d, smt);
        }
        skl = blockReduceSum256(skl); __syncthreads();
        ssz = blockReduceSum256(ssz); __syncthreads();
        smt = blockReduceSum256(smt);
        if (tid == 0) {
            ws[KL_OFF + r] = skl;
            ws[SIZ_OFF + r] = ssz;
            ws[MAT_OFF + r] = smt;
        }
    }
}

__global__ __launch_bounds__(256) void finalize_kernel(
    const float* __restrict__ ws, float* __restrict__ out) {
    const int t = threadIdx.x;
    float pp = ws[PPS_OFF + t];
    float ch = ws[CHS_OFF + t] + ws[CHS_OFF + 256 + t] +
               ws[CHS_OFF + 512 + t] + ws[CHS_OFF + 768 + t];
    float kl = (t < SL_BLOCKS) ? ws[KL_OFF + t] : 0.0f;
    float sz = (t < SL_BLOCKS) ? ws[SIZ_OFF + t] : 0.0f;
    float mt = (t < SL_BLOCKS) ? ws[MAT_OFF + t] : 0.0f;
    float s_pp = blockReduceSum256(pp); __syncthreads();
    float s_ch = blockReduceSum256(ch); __syncthreads();
    float s_kl = blockReduceSum256(kl); __syncthreads();
    float s_sz = blockReduceSum256(sz); __syncthreads();
    float s_mt = blockReduceSum256(mt);
    if (t == 0) {
        float den = 0.0f;
        #pragma unroll
        for (int b = 0; b < BB; ++b) {
            float s = ws[DNS_OFF + 4 * b + 0] + ws[DNS_OFF + 4 * b + 1] +
                      ws[DNS_OFF + 4 * b + 2] + ws[DNS_OFF + 4 * b + 3];
            float q = ws[DNS_OFF + 16 + 4 * b + 0] + ws[DNS_OFF + 16 + 4 * b + 1] +
                      ws[DNS_OFF + 16 + 4 * b + 2] + ws[DNS_OFF + 16 + 4 * b + 3];
            float var = (q - s * s / (float)NSUB) / (float)(NSUB - 1);
            den += sqrtf(fmaxf(var, 0.0f));
        }
        den *= (1.0f / BB);
        float cd = (s_pp - 2.0f * s_ch) / (float)(BB * NN);
        float klv = -0.5f * s_kl / (float)(BB * LL);
        float sizing = s_sz / (float)(BB * NN);
        float material = s_mt / (float)(BB * NN * 4);
        out[0] = cd + 0.001f * klv + 0.1f * den + 0.05f * sizing +
                 0.1f * material;
    }
}

extern "C" void kernel_launch(void* const* d_in, const int* in_sizes, int n_in,
                              void* d_out, int out_size, void* d_ws,
                              size_t ws_size, hipStream_t stream) {
    const float* pred_pos = (const float*)d_in[0];
    const float* pred_siz = (const float*)d_in[1];
    const float* pred_mat = (const float*)d_in[2];
    const float* targ_pos = (const float*)d_in[3];
    const float* targ_siz = (const float*)d_in[4];
    const float* targ_mat = (const float*)d_in[5];
    const float* mu = (const float*)d_in[6];
    const float* logvar = (const float*)d_in[7];
    const int* sub_idx = (const int*)d_in[8];
    float* out = (float*)d_out;
    float* ws = (float*)d_ws;
    unsigned char* frag = (unsigned char*)d_ws + FRAG_OFF;

    prep_frags_kernel<<<PREP_BLOCKS, 256, 0, stream>>>(pred_pos, targ_pos,
                                                       frag, ws);
    mega_kernel<<<AUX_BLOCKS + CH_BLOCKS, 256, 0, stream>>>(
        pred_pos, frag, mu, logvar, pred_siz, targ_siz, pred_mat, targ_mat,
        sub_idx, ws);
    finalize_kernel<<<1, 256, 0, stream>>>(ws, out);
}